// Round 3
// baseline (295.208 us; speedup 1.0000x reference)
//
#include <hip/hip_runtime.h>

// MultinomialDiffusion.q_posterior — structure-exploiting, fully-coalesced version.
//   log_x_t : (16,2,1,1024,1024) f32  LOG ONE-HOT  -> read plane 0 only, hot = (val > -35)
//   log_x_0 : (16,2,1,1024,1024) f32  log-softmax  -> read plane 0 only (plane1 = log(1-p))
//   schedules (1000,) f32; t (16,) int32; out (16,2,1,1024,1024) f32
// Math per position (K=2), a = alpha_bar[t-1], c = (1-alpha_bar[t-1])/2:
//   p  = exp(l00); e0 = log(a*p + c); e1 = log(a*(1-p) + c)     [t>0]
//   d  = e0 - e1   (or l00 - l01 when t==0)
//   Delta = d + (hot0 ? +delta : -delta),  delta = logaddexp(C,D) - D
//   o0 = -logaddexp(0, -Delta),  o1 = o0 - Delta
//
// V4: PERSISTENT PIPELINED STRUCTURE.
// Evidence so far: V1 (2 loads in flight), V2 (8 loads hoisted), V3 (normal
// stores, contiguous windows) all land at 78-82 us / ~2.5 TB/s EA-side, while
// fillBuffer (6.8 TB/s) and float4-copy (6.3 TB/s) prove the memory system is
// 2.5x faster for continuous streams. Little's law on the measured counters:
// ~20 waves/CU x 16KB each, wave lifetime ~25 us -> the 16384 short waves run
// as ~3 discrete generations; each CU's request stream is bursty (issue 8KB,
// drain, retire, wait for next dispatch generation). This kernel instead runs
// EXACTLY 2048 blocks (8/CU, all co-resident, no generations) and each thread
// software-pipelines 8 tiles (issue tile t+1 loads before compute/store of
// tile t) so every CU keeps requests in flight continuously, like the copy.

#define LL (1024 * 1024)
#define TILES 8
#define BLOCKS_PER_B 128              // 128 blocks x 256 thr x 8 tiles x 4 elem = 2^20
#define GRID (16 * BLOCKS_PER_B)      // 2048 = 8 blocks/CU exactly

typedef float vfloat4 __attribute__((ext_vector_type(4)));

__global__ __launch_bounds__(256) void qposterior_kernel(
    const float* __restrict__ lxt,
    const float* __restrict__ lx0,
    const float* __restrict__ la,
    const float* __restrict__ l1a,
    const float* __restrict__ lab,
    const float* __restrict__ l1ab,
    const int* __restrict__ tarr,
    float* __restrict__ out)
{
    const float LOGK = 0.6931471805599453f; // log(2)

    int bid   = blockIdx.x;
    int b     = bid >> 7;                 // 128 blocks per batch
    int local = bid & (BLOCKS_PER_B - 1);

    // ---- per-batch scalars (wave-uniform) ----
    int tb = tarr[b];
    bool t0 = (tb == 0);
    float C = la[tb];
    float D = l1a[tb] - LOGK;
    float mm = fmaxf(C, D);
    float s_hot = mm + __logf(1.0f + __expf(fminf(C, D) - mm));
    float delta = s_hot - D;              // logaddexp(C,D) - D

    float a = 0.f, c = 0.f, apc = 0.f;
    if (!t0) {
        int tm1 = tb - 1;
        a   = __expf(lab[tm1]);           // alpha_bar[t-1]
        c   = 0.5f * __expf(l1ab[tm1]);   // (1 - alpha_bar[t-1]) / 2
        apc = a + c;
    }

    const float* xt_p  = lxt + b * (2 * LL);
    const float* x0_p  = lx0 + b * (2 * LL);
    float*       out_p = out + b * (2 * LL);

    // Contiguous 32KB window per block per stream:
    // group index = local*2048 + t*256 + tid, element offset = group*4.
    int gbase = local * (TILES * 256) + threadIdx.x;

    if (!t0) {
        // ================= hot path (t > 0), software-pipelined =================
        int e0i = gbase * 4;
        vfloat4 xt_c = *reinterpret_cast<const vfloat4*>(xt_p + e0i);
        vfloat4 x0_c = *reinterpret_cast<const vfloat4*>(x0_p + e0i);

#pragma unroll
        for (int t = 0; t < TILES; ++t) {
            int e  = (gbase + t * 256) * 4;
            // ---- issue NEXT tile's loads before touching current data ----
            vfloat4 xt_n = xt_c, x0_n = x0_c;
            if (t + 1 < TILES) {
                int en = (gbase + (t + 1) * 256) * 4;
                xt_n = *reinterpret_cast<const vfloat4*>(xt_p + en);
                x0_n = *reinterpret_cast<const vfloat4*>(x0_p + en);
            }
            // Pin the schedule: next-tile loads stay ABOVE current compute.
            __builtin_amdgcn_sched_barrier(0);

            vfloat4 r0, r1;
#pragma unroll
            for (int i = 0; i < 4; ++i) {
                float l00 = x0_c[i];
                float p  = __expf(l00);
                float ee0 = __logf(fmaf(a, p, c));
                float ee1 = __logf(fmaf(-a, p, apc));
                float d  = ee0 - ee1;
                float sd    = (xt_c[i] > -35.0f) ? delta : -delta;
                float Delta = d + sd;
                // o0 = -logaddexp(0, -Delta)
                float m  = fmaxf(-Delta, 0.0f);
                float o0 = -(m + __logf(1.0f + __expf(-fabsf(Delta))));
                r0[i] = o0;
                r1[i] = o0 - Delta;
            }
            *reinterpret_cast<vfloat4*>(out_p + e)      = r0;
            *reinterpret_cast<vfloat4*>(out_p + e + LL) = r1;

            xt_c = xt_n;   // full unroll -> pure register rotation
            x0_c = x0_n;
        }
    } else {
        // ================= t == 0 path (rare; uniform per batch) =================
        // d = log_x_0[class0] - log_x_0[class1]; needs plane-1 reads. Kept in a
        // separate uniform branch so its loads don't inflate hot-path registers.
#pragma unroll
        for (int t = 0; t < TILES; ++t) {
            int e = (gbase + t * 256) * 4;
            vfloat4 xt = *reinterpret_cast<const vfloat4*>(xt_p + e);
            vfloat4 x0 = *reinterpret_cast<const vfloat4*>(x0_p + e);
            vfloat4 x1 = *reinterpret_cast<const vfloat4*>(x0_p + e + LL);
            vfloat4 r0, r1;
#pragma unroll
            for (int i = 0; i < 4; ++i) {
                float d = x0[i] - x1[i];
                float sd    = (xt[i] > -35.0f) ? delta : -delta;
                float Delta = d + sd;
                float m  = fmaxf(-Delta, 0.0f);
                float o0 = -(m + __logf(1.0f + __expf(-fabsf(Delta))));
                r0[i] = o0;
                r1[i] = o0 - Delta;
            }
            *reinterpret_cast<vfloat4*>(out_p + e)      = r0;
            *reinterpret_cast<vfloat4*>(out_p + e + LL) = r1;
        }
    }
}

extern "C" void kernel_launch(void* const* d_in, const int* in_sizes, int n_in,
                              void* d_out, int out_size, void* d_ws, size_t ws_size,
                              hipStream_t stream) {
    const float* lxt  = (const float*)d_in[0];
    const float* lx0  = (const float*)d_in[1];
    const float* la   = (const float*)d_in[2];
    const float* l1a  = (const float*)d_in[3];
    const float* lab  = (const float*)d_in[4];
    const float* l1ab = (const float*)d_in[5];
    const int*   tarr = (const int*)d_in[6];
    float*       out  = (float*)d_out;

    qposterior_kernel<<<GRID, 256, 0, stream>>>(lxt, lx0, la, l1a, lab, l1ab, tarr, out);
}